// Round 14
// baseline (24.707 us; speedup 1.0000x reference)
//
#include <hip/hip_runtime.h>

#define BB 16
#define NN 65536
#define KK 64
#define TPB 512
#define E   2048                  // elements per segment (4/thread, one float4)
#define SEGS 32                   // segments per row
#define NBLK (BB * SEGS / 2)      // 256 blocks: each owns a (p, 31-p) pair
#define W   14336                 // LDS window floats (56 KB)
#define SPANMAX (W - E - 8)       // max lag-span per batch

__device__ __forceinline__ float readlane_f(float v, int lane) {
    return __uint_as_float((unsigned)__builtin_amdgcn_readlane((int)__float_as_uint(v), lane));
}

__global__ __launch_bounds__(TPB) void frac_deriv_kernel(
    const float* __restrict__ x,
    const float* __restrict__ loc,
    const float* __restrict__ scale,
    const float* __restrict__ eps,
    const int* __restrict__ lags,
    float* __restrict__ out)
{
    __shared__ float win[W];
    __shared__ int   js_raw[KK];
    __shared__ float ws_raw[KK];
    __shared__ int   js[KK];
    __shared__ float ws[KK];

    const int tid  = threadIdx.x;
    const int lane = tid & 63;

    // Bijective XCD swizzle over 256 blocks (32/XCD).
    const int bid = blockIdx.x;
    const int swz = (bid & 7) * (NBLK / 8) + (bid >> 3);
    const int b   = swz >> 4;            // row [0,16)
    const int p   = swz & 15;            // pair index
    const int TA  = p * E;               // light segment
    const int TB  = (SEGS - 1 - p) * E;  // heavy segment (balanced pair)

    const float* __restrict__ xr = x + (size_t)b * NN;
    const int eA = TA + 4 * tid;
    const int eB = TB + 4 * tid;
    float4 xtA, xtB;
    __builtin_memcpy(&xtA, xr + eA, 16);   // early issue
    __builtin_memcpy(&xtB, xr + eB, 16);

    // --- Prologue: wave 0 computes f64 weights, rank-sorts lags.
    if (tid < KK) {
        double s  = (double)scale[0];
        double sp = (s > 20.0) ? s : log1p(exp(s));
        double a  = (double)loc[0] + sp * (double)eps[0];
        a = fmin(fmax(a, 0.01), 0.99);
        double c = a * exp(-lgamma(1.0 - a)) * ((double)(NN - 1) / (double)KK);
        int j = lags[tid];
        j = (j < 1) ? 1 : ((j > NN - 1) ? NN - 1 : j);
        js_raw[tid] = j;
        ws_raw[tid] = (float)(c * exp(-(a + 1.0) * log((double)j)));
    }
    __syncthreads();
    if (tid < KK) {
        const int j = js_raw[tid];
        int rank = 0;
        for (int k = 0; k < KK; ++k) {
            const int jk = js_raw[k];
            rank += (int)((jk < j) || (jk == j && k < tid));
        }
        js[rank] = j;
        ws[rank] = ws_raw[tid];
    }
    __syncthreads();

    const int   jv = js[lane];           // identical content in every wave
    const float wv = ws[lane];
    const int tid4 = 4 * tid;

    float* __restrict__ orow = out + (size_t)b * NN;

    // ---- Per-segment processing: batched LDS sliding window, descending lags.
    auto process_seg = [&](const int T, const float4 xt, const int e0) {
        const int cf = __popcll(__ballot(jv <= T));
        const int cp = __popcll(__ballot(jv <= T + (E - 1)));

        double a0 = 0.0, a1 = 0.0, a2 = 0.0, a3 = 0.0;

        int m_hi = cf - 1;
        while (m_hi >= 0) {
            const int J_hi = __builtin_amdgcn_readlane(jv, m_hi);
            // extend batch: lags with j >= J_hi - SPANMAX (sorted -> prefix index)
            const int X    = J_hi - SPANMAX;
            const int nge  = __popcll(__ballot(jv >= X));
            int m_lo = KK - nge;
            if (m_lo < 0) m_lo = 0;
            const int J_lo = __builtin_amdgcn_readlane(jv, m_lo);

            // stage [s4, e4) -> win[0..): aligned float4 copies, coalesced
            const int s4 = (T - J_hi) & ~3;
            const int e_end = T - J_lo + E;
            const int e4 = (e_end + 3) & ~3;
            __syncthreads();                      // prior batch reads done
            for (int i = s4 + tid4; i < e4; i += 4 * TPB) {
                float4 v;
                __builtin_memcpy(&v, xr + i, 16);
                *(float4*)&win[i - s4] = v;
            }
            __syncthreads();                      // staged data visible

            // consume: descending lags, 8-lag groups, f32 -> f64 flush
            const int base_s = T - s4;            // scalar; per-lag off = base_s - j
            int m = m_hi;
            for (; m - 7 >= m_lo; m -= 8) {
                float g0 = 0.f, g1 = 0.f, g2 = 0.f, g3 = 0.f;
#pragma unroll
                for (int k = 0; k < 8; ++k) {
                    const int   jj = __builtin_amdgcn_readlane(jv, m - k);
                    const float wm = readlane_f(wv, m - k);
                    const int idx = base_s - jj + tid4;
                    const float u0 = win[idx];
                    const float u1 = win[idx + 1];
                    const float u2 = win[idx + 2];
                    const float u3 = win[idx + 3];
                    g0 = fmaf(xt.x - u0, wm, g0);
                    g1 = fmaf(xt.y - u1, wm, g1);
                    g2 = fmaf(xt.z - u2, wm, g2);
                    g3 = fmaf(xt.w - u3, wm, g3);
                }
                a0 += (double)g0; a1 += (double)g1;
                a2 += (double)g2; a3 += (double)g3;
            }
            {
                float g0 = 0.f, g1 = 0.f, g2 = 0.f, g3 = 0.f;
                for (; m >= m_lo; --m) {
                    const int   jj = __builtin_amdgcn_readlane(jv, m);
                    const float wm = readlane_f(wv, m);
                    const int idx = base_s - jj + tid4;
                    const float u0 = win[idx];
                    const float u1 = win[idx + 1];
                    const float u2 = win[idx + 2];
                    const float u3 = win[idx + 3];
                    g0 = fmaf(xt.x - u0, wm, g0);
                    g1 = fmaf(xt.y - u1, wm, g1);
                    g2 = fmaf(xt.z - u2, wm, g2);
                    g3 = fmaf(xt.w - u3, wm, g3);
                }
                a0 += (double)g0; a1 += (double)g1;
                a2 += (double)g2; a3 += (double)g3;
            }
            m_hi = m_lo - 1;
        }

        // straddle lags (T < j <= T+E-1): global masked path (~2 lags)
        for (int m = cf; m < cp; ++m) {
            const int   jj = __builtin_amdgcn_readlane(jv, m);
            const float wm = readlane_f(wv, m);
            const int d0 = e0 - jj;
            const float u0 = xr[(d0     < 0) ? 0 : d0];
            const float u1 = xr[(d0 + 1 < 0) ? 0 : d0 + 1];
            const float u2 = xr[(d0 + 2 < 0) ? 0 : d0 + 2];
            const float u3 = xr[(d0 + 3 < 0) ? 0 : d0 + 3];
            a0 += (d0     >= 0) ? (double)((xt.x - u0) * wm) : 0.0;
            a1 += (d0 + 1 >= 0) ? (double)((xt.y - u1) * wm) : 0.0;
            a2 += (d0 + 2 >= 0) ? (double)((xt.z - u2) * wm) : 0.0;
            a3 += (d0 + 3 >= 0) ? (double)((xt.w - u3) * wm) : 0.0;
        }

        float4 r = make_float4((float)a0, (float)a1, (float)a2, (float)a3);
        __builtin_memcpy(orow + e0, &r, 16);
    };

    process_seg(TA, xtA, eA);
    __syncthreads();               // A's window reads complete before B re-stages
    process_seg(TB, xtB, eB);
}

extern "C" void kernel_launch(void* const* d_in, const int* in_sizes, int n_in,
                              void* d_out, int out_size, void* d_ws, size_t ws_size,
                              hipStream_t stream) {
    const float* x     = (const float*)d_in[0];
    const float* loc   = (const float*)d_in[1];
    const float* scale = (const float*)d_in[2];
    const float* eps   = (const float*)d_in[3];
    const int*   lags  = (const int*)d_in[4];
    float* out = (float*)d_out;

    frac_deriv_kernel<<<NBLK, TPB, 0, stream>>>(x, loc, scale, eps, lags, out);
}

// Round 15
// 16.291 us; speedup vs baseline: 1.5166x; 1.5166x over previous
//
#include <hip/hip_runtime.h>

#define BB 16
#define NN 65536
#define KK 64
#define TPB 256
#define EPB 1024                  // 4 elems/thread (one float4)
#define NBLK ((BB * NN) / EPB)    // 1024 blocks = 4/CU, 16 waves/CU

__device__ __forceinline__ float readlane_f(float v, int lane) {
    return __uint_as_float((unsigned)__builtin_amdgcn_readlane((int)__float_as_uint(v), lane));
}

__device__ __forceinline__ float4 load4(const float* p) {
    float4 v;
    __builtin_memcpy(&v, p, 16);   // global_load_dwordx4 (align-4 legal on gfx9+)
    return v;
}

__global__ __launch_bounds__(TPB) void frac_deriv_kernel(
    const float* __restrict__ x,
    const float* __restrict__ loc,
    const float* __restrict__ scale,
    const float* __restrict__ eps,
    const int* __restrict__ lags,
    float* __restrict__ out)
{
    __shared__ int   js_raw[KK];
    __shared__ float ws_raw[KK];
    __shared__ int   js[KK];
    __shared__ float ws[KK];

    const int tid  = threadIdx.x;
    const int lane = tid & 63;

    // Bijective XCD swizzle: 1024 blocks -> 128/XCD = 2 rows per XCD L2;
    // heavy-first within each XCD chunk for backfill balance.
    const int bid = blockIdx.x;
    const int swz = (bid & 7) * (NBLK / 8) + (bid >> 3);
    const int b   = swz >> 6;          // row [0,16)
    const int q   = 63 - (swz & 63);   // heavy-first
    const int T   = q * EPB;

    const float* __restrict__ xr = x + (size_t)b * NN;
    const int e0 = T + 4 * tid;
    float4 xt;
    __builtin_memcpy(&xt, xr + e0, 16);  // issued early; hides under prologue

    // --- Prologue: wave 0 computes f64 weights and rank-sorts lags (measured free).
    if (tid < KK) {
        double s  = (double)scale[0];
        double sp = (s > 20.0) ? s : log1p(exp(s));
        double a  = (double)loc[0] + sp * (double)eps[0];
        a = fmin(fmax(a, 0.01), 0.99);
        double c = a * exp(-lgamma(1.0 - a)) * ((double)(NN - 1) / (double)KK);
        int j = lags[tid];
        j = (j < 1) ? 1 : ((j > NN - 1) ? NN - 1 : j);
        js_raw[tid] = j;
        ws_raw[tid] = (float)(c * exp(-(a + 1.0) * log((double)j)));
    }
    __syncthreads();
    if (tid < KK) {
        const int j = js_raw[tid];
        int rank = 0;
        for (int k = 0; k < KK; ++k) {
            const int jk = js_raw[k];
            rank += (int)((jk < j) || (jk == j && k < tid));
        }
        js[rank] = j;
        ws[rank] = ws_raw[tid];
    }
    __syncthreads();

    const int   jv = js[lane];
    const float wv = ws[lane];
    const int cf = __popcll(__ballot(jv <= T));             // fully-valid prefix
    const int cp = __popcll(__ballot(jv <= T + (EPB - 1))); // incl. straddle
    const int cf8 = cf & ~7;

    double a0 = 0.0, a1 = 0.0, a2 = 0.0, a3 = 0.0;

    // --- Fully-valid lags: ONE dwordx4 gather per lag per wave; 8-lag groups,
    //     f32 partials flushed to f64 (absmax 1.2e-4, 8x under threshold).
    for (int mo = 0; mo < cf8; mo += 8) {
        float4 g = make_float4(0.f, 0.f, 0.f, 0.f);
#pragma unroll
        for (int mi = 0; mi < 8; ++mi) {
            const int   m  = mo + mi;
            const int   jj = __builtin_amdgcn_readlane(jv, m);
            const float w  = readlane_f(wv, m);
            const float4 xg = load4(xr + (e0 - jj));   // SGPR base + shared voffset
            g.x = fmaf(xt.x - xg.x, w, g.x);
            g.y = fmaf(xt.y - xg.y, w, g.y);
            g.z = fmaf(xt.z - xg.z, w, g.z);
            g.w = fmaf(xt.w - xg.w, w, g.w);
        }
        a0 += (double)g.x; a1 += (double)g.y; a2 += (double)g.z; a3 += (double)g.w;
    }
    // Remainder of fully-valid lags.
    for (int m = cf8; m < cf; ++m) {
        const int   jj = __builtin_amdgcn_readlane(jv, m);
        const float w  = readlane_f(wv, m);
        const float4 xg = load4(xr + (e0 - jj));
        a0 += (double)((xt.x - xg.x) * w);
        a1 += (double)((xt.y - xg.y) * w);
        a2 += (double)((xt.z - xg.z) * w);
        a3 += (double)((xt.w - xg.w) * w);
    }
    // Straddle lags (T < j <= T+EPB-1): per-element masked clamp (~1 lag typical).
    for (int m = cf; m < cp; ++m) {
        const int   jj = __builtin_amdgcn_readlane(jv, m);
        const float w  = readlane_f(wv, m);
        const int d0 = e0 - jj;
        const float g0 = xr[(d0     < 0) ? 0 : d0];
        const float g1 = xr[(d0 + 1 < 0) ? 0 : d0 + 1];
        const float g2 = xr[(d0 + 2 < 0) ? 0 : d0 + 2];
        const float g3 = xr[(d0 + 3 < 0) ? 0 : d0 + 3];
        a0 += (d0     >= 0) ? (double)((xt.x - g0) * w) : 0.0;
        a1 += (d0 + 1 >= 0) ? (double)((xt.y - g1) * w) : 0.0;
        a2 += (d0 + 2 >= 0) ? (double)((xt.z - g2) * w) : 0.0;
        a3 += (d0 + 3 >= 0) ? (double)((xt.w - g3) * w) : 0.0;
    }

    float4 r = make_float4((float)a0, (float)a1, (float)a2, (float)a3);
    __builtin_memcpy(out + (size_t)b * NN + e0, &r, 16);
}

extern "C" void kernel_launch(void* const* d_in, const int* in_sizes, int n_in,
                              void* d_out, int out_size, void* d_ws, size_t ws_size,
                              hipStream_t stream) {
    const float* x     = (const float*)d_in[0];
    const float* loc   = (const float*)d_in[1];
    const float* scale = (const float*)d_in[2];
    const float* eps   = (const float*)d_in[3];
    const int*   lags  = (const int*)d_in[4];
    float* out = (float*)d_out;

    frac_deriv_kernel<<<NBLK, TPB, 0, stream>>>(x, loc, scale, eps, lags, out);
}